// Round 17
// baseline (115.271 us; speedup 1.0000x reference)
//
#include <hip/hip_runtime.h>

// PhysicsGuidedAttention: B=2, N=2048, D=768, H=12, Hd=64
// qkv = x @ w_qkv.T ; flash-attn with elevation bias ; out = attn_out @ w_proj.T + b_proj
// R17: attn = R12 8-wave body + grid-level kv-split z=2 (384 blocks, 3072 waves,
//      same per-thread staging). Pure-sum partials: O (f32) -> P0/d_out, psum
//      from ones-MFMA regs; R8-proven combine -> aob. gemm2 converts w_proj f32
//      in staging regs (frees wprojb; ws = 41.7 MB = R8-proven footprint).

typedef __attribute__((ext_vector_type(8))) short bf16x8;   // 8 bf16 = 4 VGPRs
typedef __attribute__((ext_vector_type(4))) float f32x4;
typedef __attribute__((ext_vector_type(16))) float f32x16;  // 32x32 accumulator

__device__ __forceinline__ unsigned short f2bf(float f) {
  unsigned int u = __builtin_bit_cast(unsigned int, f);
  u += 0x7fffu + ((u >> 16) & 1u);        // round-to-nearest-even
  return (unsigned short)(u >> 16);
}

__device__ __forceinline__ unsigned cvtpk(float lo, float hi) {
  unsigned r;
  asm("v_cvt_pk_bf16_f32 %0, %1, %2" : "=v"(r) : "v"(lo), "v"(hi));
  return r;
}

__device__ __forceinline__ float exp2v(float x) {
  float r;
  asm("v_exp_f32 %0, %1" : "=v"(r) : "v"(x));
  return r;
}

// XOR swizzle on element index: spreads 128B-stride row slots across banks.
__device__ __forceinline__ int sw8(int row) {
  return ((row ^ (row >> 3)) & 7) << 3;
}

__device__ __forceinline__ void gload16(const unsigned short* g, unsigned short* l) {
  __builtin_amdgcn_global_load_lds(
      (const __attribute__((address_space(1))) unsigned int*)g,
      (__attribute__((address_space(3))) unsigned int*)l, 16, 0, 0);
}

// ---------------------------------------------------------------------------
// f32 -> bf16 convert (w_qkv only; x handled in gemm1, w_proj in gemm2).
__global__ __launch_bounds__(256)
void cvt_kernel(const float* __restrict__ in, unsigned short* __restrict__ out, int n8) {
  const int i = blockIdx.x * 256 + threadIdx.x;
  if (i >= n8) return;
  const float4 f0 = ((const float4*)in)[i * 2];
  const float4 f1 = ((const float4*)in)[i * 2 + 1];
  uint4 v;
  v.x = cvtpk(f0.x, f0.y);
  v.y = cvtpk(f0.z, f0.w);
  v.z = cvtpk(f1.x, f1.y);
  v.w = cvtpk(f1.z, f1.w);
  ((uint4*)out)[i] = v;
}

// ---------------------------------------------------------------------------
// gemm1: C[M,N] = A[M,K] @ B[N,K]^T with A = f32 (converted in staging regs),
// B bf16 via gload_lds, C bf16. 128x128 tile, BK=32, 2-phase dbuf (T14 for A).
__global__ __launch_bounds__(256)
void gemm_a32_kernel(const float* __restrict__ Ap,
                     const unsigned short* __restrict__ Bp,
                     unsigned short* __restrict__ Cp, int M, int N, int K) {
  __shared__ __align__(16) unsigned short lds_a[2][128 * 32];
  __shared__ __align__(16) unsigned short lds_b[2][128 * 32];
  const int t = threadIdx.x;
  const int l = t & 63;
  const int w = t >> 6;
  const int wr = w >> 1, wc = w & 1;
  const int bid = blockIdx.x + gridDim.x * blockIdx.y;
  const int xcd = bid & 7;
  const int idx = bid >> 3;
  const int brow = (xcd * 4 + (idx & 3)) * 128;
  const int bcol = (idx >> 2) * 128;
  const int l15 = l & 15, l4 = l >> 4;

  const int srow = t >> 2;
  const int scol = (t & 3) * 8;
  const float* ga = Ap + (size_t)(brow + srow) * K + scol;
  const unsigned short* gb = Bp + (size_t)(bcol + srow) * K + scol;

  f32x4 acc[4][4] = {};
  const int nk = K >> 5;

  float4 fa[4];
  {
    fa[0] = *(const float4*)ga;
    fa[1] = *(const float4*)(ga + 4);
    fa[2] = *(const float4*)(ga + (size_t)64 * K);
    fa[3] = *(const float4*)(ga + (size_t)64 * K + 4);
    unsigned short* lb = lds_b[0] + w * 512;
    gload16(gb, lb);
    gload16(gb + (size_t)64 * K, lb + 2048);
    uint4 u0, u1;
    u0.x = cvtpk(fa[0].x, fa[0].y); u0.y = cvtpk(fa[0].z, fa[0].w);
    u0.z = cvtpk(fa[1].x, fa[1].y); u0.w = cvtpk(fa[1].z, fa[1].w);
    u1.x = cvtpk(fa[2].x, fa[2].y); u1.y = cvtpk(fa[2].z, fa[2].w);
    u1.z = cvtpk(fa[3].x, fa[3].y); u1.w = cvtpk(fa[3].z, fa[3].w);
    *(uint4*)&lds_a[0][srow * 32 + scol] = u0;
    *(uint4*)&lds_a[0][(srow + 64) * 32 + scol] = u1;
  }
  __syncthreads();

  int buf = 0;
  for (int kt = 0; kt < nk; ++kt) {
    const bool more = kt + 1 < nk;
    if (more) {
      const size_t ko = (size_t)(kt + 1) * 32;
      fa[0] = *(const float4*)(ga + ko);
      fa[1] = *(const float4*)(ga + ko + 4);
      fa[2] = *(const float4*)(ga + ko + (size_t)64 * K);
      fa[3] = *(const float4*)(ga + ko + (size_t)64 * K + 4);
      unsigned short* lb = lds_b[buf ^ 1] + w * 512;
      gload16(gb + ko, lb);
      gload16(gb + ko + (size_t)64 * K, lb + 2048);
    }
    bf16x8 af[4], bfr[4];
#pragma unroll
    for (int i = 0; i < 4; ++i) {
      af[i]  = *(const bf16x8*)&lds_a[buf][(wr * 64 + i * 16 + l15) * 32 + l4 * 8];
      bfr[i] = *(const bf16x8*)&lds_b[buf][(wc * 64 + i * 16 + l15) * 32 + l4 * 8];
    }
#pragma unroll
    for (int i = 0; i < 4; ++i)
#pragma unroll
      for (int j = 0; j < 4; ++j)
        acc[i][j] = __builtin_amdgcn_mfma_f32_16x16x32_bf16(af[i], bfr[j], acc[i][j], 0, 0, 0);
    if (more) {
      uint4 u0, u1;
      u0.x = cvtpk(fa[0].x, fa[0].y); u0.y = cvtpk(fa[0].z, fa[0].w);
      u0.z = cvtpk(fa[1].x, fa[1].y); u0.w = cvtpk(fa[1].z, fa[1].w);
      u1.x = cvtpk(fa[2].x, fa[2].y); u1.y = cvtpk(fa[2].z, fa[2].w);
      u1.z = cvtpk(fa[3].x, fa[3].y); u1.w = cvtpk(fa[3].z, fa[3].w);
      *(uint4*)&lds_a[buf ^ 1][srow * 32 + scol] = u0;
      *(uint4*)&lds_a[buf ^ 1][(srow + 64) * 32 + scol] = u1;
    }
    __syncthreads();
    buf ^= 1;
  }

#pragma unroll
  for (int i = 0; i < 4; ++i)
#pragma unroll
    for (int j = 0; j < 4; ++j)
#pragma unroll
      for (int r = 0; r < 4; ++r) {
        const int row = brow + wr * 64 + i * 16 + l4 * 4 + r;
        const int col = bcol + wc * 64 + j * 16 + l15;
        Cp[(size_t)row * N + col] = f2bf(acc[i][j][r]);
      }
}

// ---------------------------------------------------------------------------
// gemm2: C[M,N] = A[M,K] @ B[N,K]^T + bias; A bf16 via gload_lds, B = f32
// converted in staging regs (T14 late-write), C f32. 64x128 tile, BK=32.
__global__ __launch_bounds__(256)
void gemm2_kernel(const unsigned short* __restrict__ Ap,
                  const float* __restrict__ Bp,
                  const float* __restrict__ bias, float* __restrict__ Cp,
                  int M, int N, int K) {
  __shared__ __align__(16) unsigned short lds_a[2][64 * 32];
  __shared__ __align__(16) unsigned short lds_b[2][128 * 32];
  const int t = threadIdx.x;
  const int l = t & 63;
  const int w = t >> 6;
  const int wr = w >> 1, wc = w & 1;          // wave: rows wr*32, cols wc*64
  const int brow = blockIdx.x * 64;
  const int bcol = blockIdx.y * 128;
  const int l15 = l & 15, l4 = l >> 4;

  const int srow = t >> 2;
  const int scol = (t & 3) * 8;
  const unsigned short* ga = Ap + (size_t)(brow + srow) * K + scol;
  const float* gbf = Bp + (size_t)(bcol + srow) * K + scol;

  f32x4 acc[2][4] = {};
  const int nk = K >> 5;

  float4 fb[4];
  {
    gload16(ga, lds_a[0] + w * 512);
    fb[0] = *(const float4*)gbf;
    fb[1] = *(const float4*)(gbf + 4);
    fb[2] = *(const float4*)(gbf + (size_t)64 * K);
    fb[3] = *(const float4*)(gbf + (size_t)64 * K + 4);
    uint4 u0, u1;
    u0.x = cvtpk(fb[0].x, fb[0].y); u0.y = cvtpk(fb[0].z, fb[0].w);
    u0.z = cvtpk(fb[1].x, fb[1].y); u0.w = cvtpk(fb[1].z, fb[1].w);
    u1.x = cvtpk(fb[2].x, fb[2].y); u1.y = cvtpk(fb[2].z, fb[2].w);
    u1.z = cvtpk(fb[3].x, fb[3].y); u1.w = cvtpk(fb[3].z, fb[3].w);
    *(uint4*)&lds_b[0][srow * 32 + scol] = u0;
    *(uint4*)&lds_b[0][(srow + 64) * 32 + scol] = u1;
  }
  __syncthreads();

  int buf = 0;
  for (int kt = 0; kt < nk; ++kt) {
    const bool more = kt + 1 < nk;
    if (more) {
      const size_t ko = (size_t)(kt + 1) * 32;
      gload16(ga + ko, lds_a[buf ^ 1] + w * 512);
      fb[0] = *(const float4*)(gbf + ko);
      fb[1] = *(const float4*)(gbf + ko + 4);
      fb[2] = *(const float4*)(gbf + ko + (size_t)64 * K);
      fb[3] = *(const float4*)(gbf + ko + (size_t)64 * K + 4);
    }
    bf16x8 af[2], bfr[4];
#pragma unroll
    for (int i = 0; i < 2; ++i)
      af[i] = *(const bf16x8*)&lds_a[buf][(wr * 32 + i * 16 + l15) * 32 + l4 * 8];
#pragma unroll
    for (int j = 0; j < 4; ++j)
      bfr[j] = *(const bf16x8*)&lds_b[buf][(wc * 64 + j * 16 + l15) * 32 + l4 * 8];
#pragma unroll
    for (int i = 0; i < 2; ++i)
#pragma unroll
      for (int j = 0; j < 4; ++j)
        acc[i][j] = __builtin_amdgcn_mfma_f32_16x16x32_bf16(af[i], bfr[j], acc[i][j], 0, 0, 0);
    if (more) {
      uint4 u0, u1;
      u0.x = cvtpk(fb[0].x, fb[0].y); u0.y = cvtpk(fb[0].z, fb[0].w);
      u0.z = cvtpk(fb[1].x, fb[1].y); u0.w = cvtpk(fb[1].z, fb[1].w);
      u1.x = cvtpk(fb[2].x, fb[2].y); u1.y = cvtpk(fb[2].z, fb[2].w);
      u1.z = cvtpk(fb[3].x, fb[3].y); u1.w = cvtpk(fb[3].z, fb[3].w);
      *(uint4*)&lds_b[buf ^ 1][srow * 32 + scol] = u0;
      *(uint4*)&lds_b[buf ^ 1][(srow + 64) * 32 + scol] = u1;
    }
    __syncthreads();
    buf ^= 1;
  }

#pragma unroll
  for (int i = 0; i < 2; ++i)
#pragma unroll
    for (int j = 0; j < 4; ++j)
#pragma unroll
      for (int r = 0; r < 4; ++r) {
        const int row = brow + wr * 32 + i * 16 + l4 * 4 + r;
        const int col = bcol + wc * 64 + j * 16 + l15;
        Cp[(size_t)row * N + col] = acc[i][j][r] + bias[col];
      }
}

// ---------------------------------------------------------------------------
// Flash attention (R12 body), kv-split z=2. grid = (B*H, N/256, 2); 512 thr =
// 8 waves; wave w owns q [q0+32w, +32); half z does kv tiles [16z, 16z+16).
// Pure-sum partials: unnormalized O (f32) + psum (ones-MFMA regs).
__global__ __launch_bounds__(512)
void attn_kernel(const unsigned short* __restrict__ qkv,
                 const float* __restrict__ elev,
                 const float* __restrict__ alpha_p,
                 float* __restrict__ O0, float* __restrict__ O1,
                 float* __restrict__ psums) {
  __shared__ __align__(16) unsigned short lds_k[2][64 * 64];
  __shared__ __align__(16) unsigned short lds_vt[2][64 * 64];   // [d][kv], swizzled
  __shared__ __align__(16) float lds_ej[2][64];

  const int t = threadIdx.x;
  const int l = t & 63;
  const int w = t >> 6;                    // 0..7
  const int l31 = l & 31;
  const int h = l >> 5;
  const int b = blockIdx.x / 12, hd = blockIdx.x % 12;
  const int q0 = blockIdx.y * 256 + w * 32;
  const int z = blockIdx.z;
  const int s_lo = z * 16, s_hi = s_lo + 16;

  const float cE = fmaxf(alpha_p[0], 0.f) * (1.4426950408889634f * 1e-3f);
  const float c1 = 0.18033688011112042f;   // 0.125 * log2(e)

  const size_t rs = 2304;
  const unsigned short* qbase = qkv + ((size_t)b * 2048) * rs + hd * 64;
  const unsigned short* kbase = qbase + 768;
  const unsigned short* vbase = qbase + 1536;

  bf16x8 qa[4];
  {
    const unsigned short* qp = qbase + (size_t)(q0 + l31) * rs + h * 8;
#pragma unroll
    for (int ks = 0; ks < 4; ++ks) qa[ks] = *(const bf16x8*)(qp + ks * 16);
  }
  const float eiv = elev[(size_t)b * 2048 + q0 + l31] * cE;

  uint4 onesu; onesu.x = onesu.y = onesu.z = onesu.w = 0x3F803F80u;
  const bf16x8 onesf = __builtin_bit_cast(bf16x8, onesu);

  f32x16 o[2] = {};
  f32x16 ps = {};

  const int sr = t >> 3;          // row 0..63
  const int sc = (t & 7) * 8;     // col

  uint4 rk, rv;
  float evn = 0.f;

  // prologue: stage tile s_lo into buf 0
  {
    const int kv0 = s_lo * 64;
    rk = *(const uint4*)(kbase + (size_t)(kv0 + sr) * rs + sc);
    rv = *(const uint4*)(vbase + (size_t)(kv0 + sr) * rs + sc);
    if (t < 64) evn = elev[(size_t)b * 2048 + kv0 + t];
    *(uint4*)&lds_k[0][sr * 64 + (sc ^ sw8(sr))] = rk;
    union { uint4 u; unsigned short s[8]; } vu; vu.u = rv;
#pragma unroll
    for (int j = 0; j < 8; ++j) {
      const int d = sc + j;
      lds_vt[0][d * 64 + (sr ^ sw8(d))] = vu.s[j];
    }
    if (t < 64) lds_ej[0][t] = evn * cE;
  }
  __syncthreads();

#define ATTN_STEP(IT, CUR, PRE)                                                \
  {                                                                            \
    if (PRE) {                                                                 \
      const int kv1 = ((IT) + 1) * 64;                                         \
      rk = *(const uint4*)(kbase + (size_t)(kv1 + sr) * rs + sc);              \
      rv = *(const uint4*)(vbase + (size_t)(kv1 + sr) * rs + sc);              \
      if (t < 64) evn = elev[(size_t)b * 2048 + kv1 + t];                      \
    }                                                                          \
    f32x16 st[2] = {};                                                         \
    __builtin_amdgcn_s_setprio(1);                                             \
    _Pragma("unroll")                                                          \
    for (int kst = 0; kst < 4; ++kst) {                                        \
      const int col = kst * 16 + h * 8;                                        \
      _Pragma("unroll")                                                        \
      for (int mb = 0; mb < 2; ++mb) {                                         \
        const int row = mb * 32 + l31;                                         \
        bf16x8 kf = *(const bf16x8*)&lds_k[CUR][row * 64 + (col ^ sw8(row))];  \
        st[mb] = __builtin_amdgcn_mfma_f32_32x32x16_bf16(kf, qa[kst], st[mb], 0, 0, 0); \
      }                                                                        \
    }                                                                          \
    __builtin_amdgcn_s_setprio(0);                                             \
    bf16x8 pa[4];                                                              \
    _Pragma("unroll")                                                          \
    for (int mb = 0; mb < 2; ++mb) {                                           \
      float p16[16];                                                           \
      _Pragma("unroll")                                                        \
      for (int rr = 0; rr < 4; ++rr) {                                         \
        const float4 ejq = *(const float4*)&lds_ej[CUR][mb * 32 + rr * 8 + h * 4]; \
        _Pragma("unroll")                                                      \
        for (int jl = 0; jl < 4; ++jl) {                                       \
          const int r = rr * 4 + jl;                                           \
          const float bm = __builtin_amdgcn_fmed3f(ejq[jl] - eiv, 0.f, 14.4269504f); \
          p16[r] = exp2v(__builtin_fmaf(st[mb][r], c1, -bm));                  \
        }                                                                      \
      }                                                                        \
      _Pragma("unroll")                                                        \
      for (int ks2 = 0; ks2 < 2; ++ks2) {                                      \
        unsigned u0 = cvtpk(p16[ks2 * 8 + 0], p16[ks2 * 8 + 1]);               \
        unsigned u1 = cvtpk(p16[ks2 * 8 + 2], p16[ks2 * 8 + 3]);               \
        unsigned v0 = cvtpk(p16[ks2 * 8 + 4], p16[ks2 * 8 + 5]);               \
        unsigned v1 = cvtpk(p16[ks2 * 8 + 6], p16[ks2 * 8 + 7]);               \
        asm volatile("v_permlane32_swap_b32 %0, %1" : "+v"(u0), "+v"(v0));     \
        asm volatile("v_permlane32_swap_b32 %0, %1" : "+v"(u1), "+v"(v1));     \
        uint4 fr; fr.x = u0; fr.y = u1; fr.z = v0; fr.w = v1;                  \
        pa[mb * 2 + ks2] = __builtin_bit_cast(bf16x8, fr);                     \
      }                                                                        \
    }                                                                          \
    __builtin_amdgcn_s_setprio(1);                                             \
    _Pragma("unroll")                                                          \
    for (int ks = 0; ks < 4; ++ks) {                                           \
      const int col = ks * 16 + h * 8;                                         \
      _Pragma("unroll")                                                        \
      for (int nb = 0; nb < 2; ++nb) {                                         \
        const int row = nb * 32 + l31;                                         \
        bf16x8 vf = *(const bf16x8*)&lds_vt[CUR][row * 64 + (col ^ sw8(row))]; \
        o[nb] = __builtin_amdgcn_mfma_f32_32x32x16_bf16(pa[ks], vf, o[nb], 0, 0, 0); \
      }                                                                        \
      ps = __builtin_amdgcn_mfma_f32_32x32x16_bf16(pa[ks], onesf, ps, 0, 0, 0); \
    }                                                                          \
    __builtin_amdgcn_s_setprio(0);                                             \
    if (PRE) {                                                                 \
      *(uint4*)&lds_k[1 - (CUR)][sr * 64 + (sc ^ sw8(sr))] = rk;               \
      union { uint4 u; unsigned short s[8]; } vu; vu.u = rv;                   \
      _Pragma("unroll")                                                        \
      for (int j = 0; j < 8; ++j) {                                            \
        const int d = sc + j;                                                  \
        lds_vt[1 - (CUR)][d * 64 + (sr ^ sw8(d))] = vu.s[j];                   \
      }                                                                        \
      if (t < 64) lds_ej[1 - (CUR)][t] = evn * cE;                             \
    }                                                                          \
    __syncthreads();                                                           \
  }

  for (int s = 0; s < 8; ++s) {
    ATTN_STEP(s_lo + 2 * s, 0, true);
    ATTN_STEP(s_lo + 2 * s + 1, 1, s < 7);
  }
#undef ATTN_STEP

  // --- partial epilogue: psums from ps regs; unnormalized f32 O ---
  const int pbase = z * (24 * 2048) + blockIdx.x * 2048;
  if (l31 == 0) {
#pragma unroll
    for (int r = 0; r < 16; ++r) {
      const int qr = (r & 3) + 8 * (r >> 2) + 4 * h;
      psums[pbase + q0 + qr] = ps[r];
    }
  }
  float* OD = z ? O1 : O0;
#pragma unroll
  for (int nb = 0; nb < 2; ++nb) {
    const int col = hd * 64 + nb * 32 + l31;
#pragma unroll
    for (int rr = 0; rr < 4; ++rr)
#pragma unroll
      for (int jl = 0; jl < 4; ++jl) {
        const int q = q0 + rr * 8 + h * 4 + jl;
        OD[((size_t)b * 2048 + q) * 768 + col] = o[nb][rr * 4 + jl];
      }
  }
}

// ---------------------------------------------------------------------------
// Combine the two kv-halves: aob = bf16((O0+O1) / (l0+l1)). grid 4096 x 192.
__global__ __launch_bounds__(192)
void combine_kernel(const float* __restrict__ O0, const float* __restrict__ O1,
                    const float* __restrict__ psums, unsigned short* __restrict__ aob) {
  const int row = blockIdx.x;              // 0..4095 = b*2048+q
  const int b = row >> 11, q = row & 2047;
  const int c = threadIdx.x * 4;
  const int hd = c >> 6;
  const int pidx = (b * 12 + hd) * 2048 + q;
  const float inv = 1.0f / (psums[pidx] + psums[24 * 2048 + pidx]);
  const size_t off = (size_t)row * 768 + c;
  const float4 a = *(const float4*)&O0[off];
  const float4 d = *(const float4*)&O1[off];
  ushort4 r;
  r.x = f2bf((a.x + d.x) * inv);
  r.y = f2bf((a.y + d.y) * inv);
  r.z = f2bf((a.z + d.z) * inv);
  r.w = f2bf((a.w + d.w) * inv);
  *(ushort4*)&aob[off] = r;
}

extern "C" void kernel_launch(void* const* d_in, const int* in_sizes, int n_in,
                              void* d_out, int out_size, void* d_ws, size_t ws_size,
                              hipStream_t stream) {
  const float* x      = (const float*)d_in[0];   // [2,2048,768]
  const float* elev   = (const float*)d_in[1];   // [2,2048]
  const float* w_qkv  = (const float*)d_in[2];   // [2304,768]
  const float* w_proj = (const float*)d_in[3];   // [768,768]
  const float* b_proj = (const float*)d_in[4];   // [768]
  const float* alpha  = (const float*)d_in[5];   // [1]
  float* out = (float*)d_out;                    // [2,2048,768] f32

  // ws layout (41.7 MB = R8-proven footprint):
  //   qkvb  : bf16 [4096,2304]   18.9 MB
  //   aob   : bf16 [4096,768]     6.3 MB
  //   wqkvb : bf16 [2304,768]     3.5 MB
  //   P0    : f32  [4096,768]    12.6 MB  (attn half-0 partial)
  //   psums : f32  [2][24*2048]   0.4 MB
  // attn half-1 partial lives in d_out (f32, dead until gemm2).
  unsigned short* qkvb  = (unsigned short*)d_ws;
  unsigned short* aob   = qkvb + (size_t)4096 * 2304;
  unsigned short* wqkvb = aob + (size_t)4096 * 768;
  float* P0    = (float*)(wqkvb + (size_t)2304 * 768);
  float* psums = P0 + (size_t)4096 * 768;

  // convert w_qkv (x converts in gemm1 staging; w_proj in gemm2 staging)
  cvt_kernel<<<864, 256, 0, stream>>>(w_qkv, wqkvb, 2304 * 768 / 8);

  // 1) qkv = x @ w_qkv^T   (A = f32 x, converted in-register)
  gemm_a32_kernel<<<dim3(32, 18), 256, 0, stream>>>(
      x, wqkvb, qkvb, 4096, 2304, 768);

  // 2) flash attention, kv-split partials
  attn_kernel<<<dim3(24, 8, 2), 512, 0, stream>>>(qkvb, elev, alpha,
                                                  P0, out, psums);

  // 2b) combine halves -> normalized bf16 aob
  combine_kernel<<<4096, 192, 0, stream>>>(P0, out, psums, aob);

  // 3) out = aob @ w_proj^T + b_proj   (B = f32 w_proj, converted in-register)
  gemm2_kernel<<<dim3(64, 6), 256, 0, stream>>>(
      aob, w_proj, b_proj, out, 4096, 768, 768);
}

// Round 18
// 100.620 us; speedup vs baseline: 1.1456x; 1.1456x over previous
//
#include <hip/hip_runtime.h>

// PhysicsGuidedAttention: B=2, N=2048, D=768, H=12, Hd=64
// qkv = x @ w_qkv.T ; flash-attn with elevation bias ; out = attn_out @ w_proj.T + b_proj
// FINAL = R12/R16 (reproduced twice at 100.2-100.4 us; attn 57.2-57.4):
//   - attn: 8-wave/512-thr blocks, 256 q each, swapped QK^T on 32x32x16 MFMA,
//     no-max log2 softmax, in-register P via cvt_pk+permlane32_swap, ones-MFMA
//     psum with per-lane normalize, dbuf + T14 reg-staging, x2-unrolled loop.
//   - gemm1: f32-A converted in staging regs (T14 late-write), B via gload_lds.
//   - gemm2: 64x128 tiles, all-bf16 gload_lds.
// Rejected by measurement: kv-split z=2 on matched body (R17: 115.3), KV-parity
// (R15: 119.9), 128-kv spans (R13: 102.6), bf16-A gemm1 (R14: 129.2), q-doubling
// (R9: 168.3), gload_lds K in attn (R4: 136.2), grid-level kv-split (R8: 128.6).

typedef __attribute__((ext_vector_type(8))) short bf16x8;   // 8 bf16 = 4 VGPRs
typedef __attribute__((ext_vector_type(4))) float f32x4;
typedef __attribute__((ext_vector_type(16))) float f32x16;  // 32x32 accumulator

__device__ __forceinline__ unsigned short f2bf(float f) {
  unsigned int u = __builtin_bit_cast(unsigned int, f);
  u += 0x7fffu + ((u >> 16) & 1u);        // round-to-nearest-even
  return (unsigned short)(u >> 16);
}

__device__ __forceinline__ unsigned cvtpk(float lo, float hi) {
  unsigned r;
  asm("v_cvt_pk_bf16_f32 %0, %1, %2" : "=v"(r) : "v"(lo), "v"(hi));
  return r;
}

__device__ __forceinline__ float exp2v(float x) {
  float r;
  asm("v_exp_f32 %0, %1" : "=v"(r) : "v"(x));
  return r;
}

// XOR swizzle on element index: spreads 128B-stride row slots across banks.
__device__ __forceinline__ int sw8(int row) {
  return ((row ^ (row >> 3)) & 7) << 3;
}

__device__ __forceinline__ void gload16(const unsigned short* g, unsigned short* l) {
  __builtin_amdgcn_global_load_lds(
      (const __attribute__((address_space(1))) unsigned int*)g,
      (__attribute__((address_space(3))) unsigned int*)l, 16, 0, 0);
}

// ---------------------------------------------------------------------------
// f32 -> bf16 converts for w_qkv and w_proj in one launch.
__global__ __launch_bounds__(256)
void cvt2_kernel(const float* __restrict__ a, unsigned short* __restrict__ ao, int na8,
                 const float* __restrict__ b, unsigned short* __restrict__ bo, int nb8) {
  int i = blockIdx.x * 256 + threadIdx.x;
  const float* src; unsigned short* dst;
  if (i < na8) { src = a; dst = ao; }
  else {
    i -= na8;
    if (i >= nb8) return;
    src = b; dst = bo;
  }
  const float4 f0 = ((const float4*)src)[i * 2];
  const float4 f1 = ((const float4*)src)[i * 2 + 1];
  uint4 v;
  v.x = cvtpk(f0.x, f0.y);
  v.y = cvtpk(f0.z, f0.w);
  v.z = cvtpk(f1.x, f1.y);
  v.w = cvtpk(f1.z, f1.w);
  ((uint4*)dst)[i] = v;
}

// ---------------------------------------------------------------------------
// gemm1: C[M,N] = A[M,K] @ B[N,K]^T with A = f32 (converted in staging regs),
// B bf16 via gload_lds, C bf16. 128x128 tile, BK=32, 2-phase dbuf (T14 for A).
__global__ __launch_bounds__(256)
void gemm_a32_kernel(const float* __restrict__ Ap,
                     const unsigned short* __restrict__ Bp,
                     unsigned short* __restrict__ Cp, int M, int N, int K) {
  __shared__ __align__(16) unsigned short lds_a[2][128 * 32];
  __shared__ __align__(16) unsigned short lds_b[2][128 * 32];
  const int t = threadIdx.x;
  const int l = t & 63;
  const int w = t >> 6;
  const int wr = w >> 1, wc = w & 1;
  const int bid = blockIdx.x + gridDim.x * blockIdx.y;   // linear dispatch order
  const int xcd = bid & 7;
  const int idx = bid >> 3;                              // 0..71
  const int brow = (xcd * 4 + (idx & 3)) * 128;
  const int bcol = (idx >> 2) * 128;
  const int l15 = l & 15, l4 = l >> 4;

  const int srow = t >> 2;
  const int scol = (t & 3) * 8;
  const float* ga = Ap + (size_t)(brow + srow) * K + scol;
  const unsigned short* gb = Bp + (size_t)(bcol + srow) * K + scol;

  f32x4 acc[4][4] = {};
  const int nk = K >> 5;

  float4 fa[4];
  // prologue: tile 0
  {
    fa[0] = *(const float4*)ga;
    fa[1] = *(const float4*)(ga + 4);
    fa[2] = *(const float4*)(ga + (size_t)64 * K);
    fa[3] = *(const float4*)(ga + (size_t)64 * K + 4);
    unsigned short* lb = lds_b[0] + w * 512;
    gload16(gb, lb);
    gload16(gb + (size_t)64 * K, lb + 2048);
    uint4 u0, u1;
    u0.x = cvtpk(fa[0].x, fa[0].y); u0.y = cvtpk(fa[0].z, fa[0].w);
    u0.z = cvtpk(fa[1].x, fa[1].y); u0.w = cvtpk(fa[1].z, fa[1].w);
    u1.x = cvtpk(fa[2].x, fa[2].y); u1.y = cvtpk(fa[2].z, fa[2].w);
    u1.z = cvtpk(fa[3].x, fa[3].y); u1.w = cvtpk(fa[3].z, fa[3].w);
    *(uint4*)&lds_a[0][srow * 32 + scol] = u0;
    *(uint4*)&lds_a[0][(srow + 64) * 32 + scol] = u1;
  }
  __syncthreads();

  int buf = 0;
  for (int kt = 0; kt < nk; ++kt) {
    const bool more = kt + 1 < nk;
    if (more) {                            // issue next-tile loads early
      const size_t ko = (size_t)(kt + 1) * 32;
      fa[0] = *(const float4*)(ga + ko);
      fa[1] = *(const float4*)(ga + ko + 4);
      fa[2] = *(const float4*)(ga + ko + (size_t)64 * K);
      fa[3] = *(const float4*)(ga + ko + (size_t)64 * K + 4);
      unsigned short* lb = lds_b[buf ^ 1] + w * 512;
      gload16(gb + ko, lb);
      gload16(gb + ko + (size_t)64 * K, lb + 2048);
    }
    bf16x8 af[4], bfr[4];
#pragma unroll
    for (int i = 0; i < 4; ++i) {
      af[i]  = *(const bf16x8*)&lds_a[buf][(wr * 64 + i * 16 + l15) * 32 + l4 * 8];
      bfr[i] = *(const bf16x8*)&lds_b[buf][(wc * 64 + i * 16 + l15) * 32 + l4 * 8];
    }
#pragma unroll
    for (int i = 0; i < 4; ++i)
#pragma unroll
      for (int j = 0; j < 4; ++j)
        acc[i][j] = __builtin_amdgcn_mfma_f32_16x16x32_bf16(af[i], bfr[j], acc[i][j], 0, 0, 0);
    if (more) {                            // T14 late-write A (hidden under MFMA)
      uint4 u0, u1;
      u0.x = cvtpk(fa[0].x, fa[0].y); u0.y = cvtpk(fa[0].z, fa[0].w);
      u0.z = cvtpk(fa[1].x, fa[1].y); u0.w = cvtpk(fa[1].z, fa[1].w);
      u1.x = cvtpk(fa[2].x, fa[2].y); u1.y = cvtpk(fa[2].z, fa[2].w);
      u1.z = cvtpk(fa[3].x, fa[3].y); u1.w = cvtpk(fa[3].z, fa[3].w);
      *(uint4*)&lds_a[buf ^ 1][srow * 32 + scol] = u0;
      *(uint4*)&lds_a[buf ^ 1][(srow + 64) * 32 + scol] = u1;
    }
    __syncthreads();
    buf ^= 1;
  }

#pragma unroll
  for (int i = 0; i < 4; ++i)
#pragma unroll
    for (int j = 0; j < 4; ++j)
#pragma unroll
      for (int r = 0; r < 4; ++r) {
        const int row = brow + wr * 64 + i * 16 + l4 * 4 + r;
        const int col = bcol + wc * 64 + j * 16 + l15;
        Cp[(size_t)row * N + col] = f2bf(acc[i][j][r]);
      }
}

// ---------------------------------------------------------------------------
// gemm2: C[M,N] = A[M,K] @ B[N,K]^T + bias, all-bf16 inputs via gload_lds,
// C f32. 64x128 tile (384 blocks at M=4096,N=768), BK=32, 2-phase dbuf.
__global__ __launch_bounds__(256)
void gemm2_kernel(const unsigned short* __restrict__ Ap,
                  const unsigned short* __restrict__ Bp,
                  const float* __restrict__ bias, float* __restrict__ Cp,
                  int M, int N, int K) {
  __shared__ __align__(16) unsigned short lds_a[2][64 * 32];
  __shared__ __align__(16) unsigned short lds_b[2][128 * 32];
  const int t = threadIdx.x;
  const int l = t & 63;
  const int w = t >> 6;
  const int wr = w >> 1, wc = w & 1;          // wave: rows wr*32, cols wc*64
  const int brow = blockIdx.x * 64;
  const int bcol = blockIdx.y * 128;
  const int l15 = l & 15, l4 = l >> 4;

  const int srow = t >> 2;
  const int scol = (t & 3) * 8;
  const unsigned short* ga = Ap + (size_t)(brow + srow) * K + scol;
  const unsigned short* gb = Bp + (size_t)(bcol + srow) * K + scol;

  f32x4 acc[2][4] = {};
  const int nk = K >> 5;

  {
    gload16(ga, lds_a[0] + w * 512);
    unsigned short* lb = lds_b[0] + w * 512;
    gload16(gb, lb);
    gload16(gb + (size_t)64 * K, lb + 2048);
  }
  __syncthreads();

  int buf = 0;
  for (int kt = 0; kt < nk; ++kt) {
    if (kt + 1 < nk) {
      const size_t ko = (size_t)(kt + 1) * 32;
      gload16(ga + ko, lds_a[buf ^ 1] + w * 512);
      unsigned short* lb = lds_b[buf ^ 1] + w * 512;
      gload16(gb + ko, lb);
      gload16(gb + ko + (size_t)64 * K, lb + 2048);
    }
    bf16x8 af[2], bfr[4];
#pragma unroll
    for (int i = 0; i < 2; ++i)
      af[i] = *(const bf16x8*)&lds_a[buf][(wr * 32 + i * 16 + l15) * 32 + l4 * 8];
#pragma unroll
    for (int j = 0; j < 4; ++j)
      bfr[j] = *(const bf16x8*)&lds_b[buf][(wc * 64 + j * 16 + l15) * 32 + l4 * 8];
#pragma unroll
    for (int i = 0; i < 2; ++i)
#pragma unroll
      for (int j = 0; j < 4; ++j)
        acc[i][j] = __builtin_amdgcn_mfma_f32_16x16x32_bf16(af[i], bfr[j], acc[i][j], 0, 0, 0);
    __syncthreads();
    buf ^= 1;
  }

#pragma unroll
  for (int i = 0; i < 2; ++i)
#pragma unroll
    for (int j = 0; j < 4; ++j)
#pragma unroll
      for (int r = 0; r < 4; ++r) {
        const int row = brow + wr * 32 + i * 16 + l4 * 4 + r;
        const int col = bcol + wc * 64 + j * 16 + l15;
        Cp[(size_t)row * N + col] = acc[i][j][r] + bias[col];
      }
}

// ---------------------------------------------------------------------------
// Flash attention: 32x32x16 MFMA, swapped QK^T, no max-tracking, ones-MFMA psum,
// x2-unrolled main loop with literal buffer indices.
// grid = (B*H, N/256); 512 thr = 8 waves; wave w owns q [q0+32w, q0+32w+32).
__global__ __launch_bounds__(512)
void attn_kernel(const unsigned short* __restrict__ qkv,
                 const float* __restrict__ elev,
                 const float* __restrict__ alpha_p,
                 unsigned short* __restrict__ aout) {
  __shared__ __align__(16) unsigned short lds_k[2][64 * 64];
  __shared__ __align__(16) unsigned short lds_vt[2][64 * 64];   // [d][kv], swizzled
  __shared__ __align__(16) float lds_ej[2][64];

  const int t = threadIdx.x;
  const int l = t & 63;
  const int w = t >> 6;                    // 0..7
  const int l31 = l & 31;
  const int h = l >> 5;
  const int b = blockIdx.x / 12, hd = blockIdx.x % 12;
  const int q0 = blockIdx.y * 256 + w * 32;

  const float cE = fmaxf(alpha_p[0], 0.f) * (1.4426950408889634f * 1e-3f);
  const float c1 = 0.18033688011112042f;   // 0.125 * log2(e)

  const size_t rs = 2304;
  const unsigned short* qbase = qkv + ((size_t)b * 2048) * rs + hd * 64;
  const unsigned short* kbase = qbase + 768;
  const unsigned short* vbase = qbase + 1536;

  bf16x8 qa[4];
  {
    const unsigned short* qp = qbase + (size_t)(q0 + l31) * rs + h * 8;
#pragma unroll
    for (int ks = 0; ks < 4; ++ks) qa[ks] = *(const bf16x8*)(qp + ks * 16);
  }
  const float eiv = elev[(size_t)b * 2048 + q0 + l31] * cE;

  uint4 onesu; onesu.x = onesu.y = onesu.z = onesu.w = 0x3F803F80u;
  const bf16x8 onesf = __builtin_bit_cast(bf16x8, onesu);

  f32x16 o[2] = {};
  f32x16 ps = {};

  const int sr = t >> 3;          // row 0..63
  const int sc = (t & 7) * 8;     // col

  uint4 rk, rv;
  float evn = 0.f;

  // prologue: stage tile 0 into buf 0
  rk = *(const uint4*)(kbase + (size_t)sr * rs + sc);
  rv = *(const uint4*)(vbase + (size_t)sr * rs + sc);
  if (t < 64) evn = elev[(size_t)b * 2048 + t];
  *(uint4*)&lds_k[0][sr * 64 + (sc ^ sw8(sr))] = rk;
  {
    union { uint4 u; unsigned short s[8]; } vu; vu.u = rv;
#pragma unroll
    for (int j = 0; j < 8; ++j) {
      const int d = sc + j;
      lds_vt[0][d * 64 + (sr ^ sw8(d))] = vu.s[j];
    }
  }
  if (t < 64) lds_ej[0][t] = evn * cE;
  __syncthreads();

#define ATTN_STEP(IT, CUR, PRE)                                                \
  {                                                                            \
    if (PRE) {                                                                 \
      const int kv1 = ((IT) + 1) * 64;                                         \
      rk = *(const uint4*)(kbase + (size_t)(kv1 + sr) * rs + sc);              \
      rv = *(const uint4*)(vbase + (size_t)(kv1 + sr) * rs + sc);              \
      if (t < 64) evn = elev[(size_t)b * 2048 + kv1 + t];                      \
    }                                                                          \
    f32x16 st[2] = {};                                                         \
    __builtin_amdgcn_s_setprio(1);                                             \
    _Pragma("unroll")                                                          \
    for (int kst = 0; kst < 4; ++kst) {                                        \
      const int col = kst * 16 + h * 8;                                        \
      _Pragma("unroll")                                                        \
      for (int mb = 0; mb < 2; ++mb) {                                         \
        const int row = mb * 32 + l31;                                         \
        bf16x8 kf = *(const bf16x8*)&lds_k[CUR][row * 64 + (col ^ sw8(row))];  \
        st[mb] = __builtin_amdgcn_mfma_f32_32x32x16_bf16(kf, qa[kst], st[mb], 0, 0, 0); \
      }                                                                        \
    }                                                                          \
    __builtin_amdgcn_s_setprio(0);                                             \
    bf16x8 pa[4];                                                              \
    _Pragma("unroll")                                                          \
    for (int mb = 0; mb < 2; ++mb) {                                           \
      float p16[16];                                                           \
      _Pragma("unroll")                                                        \
      for (int rr = 0; rr < 4; ++rr) {                                         \
        const float4 ejq = *(const float4*)&lds_ej[CUR][mb * 32 + rr * 8 + h * 4]; \
        _Pragma("unroll")                                                      \
        for (int jl = 0; jl < 4; ++jl) {                                       \
          const int r = rr * 4 + jl;                                           \
          const float bm = __builtin_amdgcn_fmed3f(ejq[jl] - eiv, 0.f, 14.4269504f); \
          p16[r] = exp2v(__builtin_fmaf(st[mb][r], c1, -bm));                  \
        }                                                                      \
      }                                                                        \
      _Pragma("unroll")                                                        \
      for (int ks2 = 0; ks2 < 2; ++ks2) {                                      \
        unsigned u0 = cvtpk(p16[ks2 * 8 + 0], p16[ks2 * 8 + 1]);               \
        unsigned u1 = cvtpk(p16[ks2 * 8 + 2], p16[ks2 * 8 + 3]);               \
        unsigned v0 = cvtpk(p16[ks2 * 8 + 4], p16[ks2 * 8 + 5]);               \
        unsigned v1 = cvtpk(p16[ks2 * 8 + 6], p16[ks2 * 8 + 7]);               \
        asm volatile("v_permlane32_swap_b32 %0, %1" : "+v"(u0), "+v"(v0));     \
        asm volatile("v_permlane32_swap_b32 %0, %1" : "+v"(u1), "+v"(v1));     \
        uint4 fr; fr.x = u0; fr.y = u1; fr.z = v0; fr.w = v1;                  \
        pa[mb * 2 + ks2] = __builtin_bit_cast(bf16x8, fr);                     \
      }                                                                        \
    }                                                                          \
    __builtin_amdgcn_s_setprio(1);                                             \
    _Pragma("unroll")                                                          \
    for (int ks = 0; ks < 4; ++ks) {                                           \
      const int col = ks * 16 + h * 8;                                         \
      _Pragma("unroll")                                                        \
      for (int nb = 0; nb < 2; ++nb) {                                         \
        const int row = nb * 32 + l31;                                         \
        bf16x8 vf = *(const bf16x8*)&lds_vt[CUR][row * 64 + (col ^ sw8(row))]; \
        o[nb] = __builtin_amdgcn_mfma_f32_32x32x16_bf16(pa[ks], vf, o[nb], 0, 0, 0); \
      }                                                                        \
      ps = __builtin_amdgcn_mfma_f32_32x32x16_bf16(pa[ks], onesf, ps, 0, 0, 0); \
    }                                                                          \
    __builtin_amdgcn_s_setprio(0);                                             \
    if (PRE) {                                                                 \
      *(uint4*)&lds_k[1 - (CUR)][sr * 64 + (sc ^ sw8(sr))] = rk;               \
      union { uint4 u; unsigned short s[8]; } vu; vu.u = rv;                   \
      _Pragma("unroll")                                                        \
      for (int j = 0; j < 8; ++j) {                                            \
        const int d = sc + j;                                                  \
        lds_vt[1 - (CUR)][d * 64 + (sr ^ sw8(d))] = vu.s[j];                   \
      }                                                                        \
      if (t < 64) lds_ej[1 - (CUR)][t] = evn * cE;                             \
    }                                                                          \
    __syncthreads();                                                           \
  }

  for (int s = 0; s < 16; ++s) {
    ATTN_STEP(2 * s, 0, true);
    ATTN_STEP(2 * s + 1, 1, s < 15);
  }
#undef ATTN_STEP

  // --- epilogue: purely per-lane normalize (ps rows == o rows), store bf16 ---
  float inv[16];
#pragma unroll
  for (int r = 0; r < 16; ++r) inv[r] = 1.0f / ps[r];
#pragma unroll
  for (int nb = 0; nb < 2; ++nb) {
    const int col = hd * 64 + nb * 32 + l31;
#pragma unroll
    for (int rr = 0; rr < 4; ++rr)
#pragma unroll
      for (int jl = 0; jl < 4; ++jl) {
        const int r = rr * 4 + jl;
        const int q = q0 + rr * 8 + h * 4 + jl;
        aout[((size_t)b * 2048 + q) * 768 + col] = f2bf(o[nb][r] * inv[r]);
      }
  }
}

extern "C" void kernel_launch(void* const* d_in, const int* in_sizes, int n_in,
                              void* d_out, int out_size, void* d_ws, size_t ws_size,
                              hipStream_t stream) {
  const float* x      = (const float*)d_in[0];   // [2,2048,768]
  const float* elev   = (const float*)d_in[1];   // [2,2048]
  const float* w_qkv  = (const float*)d_in[2];   // [2304,768]
  const float* w_proj = (const float*)d_in[3];   // [768,768]
  const float* b_proj = (const float*)d_in[4];   // [768]
  const float* alpha  = (const float*)d_in[5];   // [1]
  float* out = (float*)d_out;                    // [2,2048,768] f32

  // ws layout (bf16): qkvb [4096,2304] ; aob [4096,768] ; wqkvb [2304,768] ;
  // wprojb [768,768]  => 29.9 MB total
  unsigned short* qkvb   = (unsigned short*)d_ws;
  unsigned short* aob    = qkvb + (size_t)4096 * 2304;
  unsigned short* wqkvb  = aob + (size_t)4096 * 768;
  unsigned short* wprojb = wqkvb + (size_t)2304 * 768;

  // convert the two weight matrices (x is converted inside gemm1 staging)
  cvt2_kernel<<<1152, 256, 0, stream>>>(w_qkv, wqkvb, 2304 * 768 / 8,
                                        w_proj, wprojb, 768 * 768 / 8);

  // 1) qkv = x @ w_qkv^T   (A = f32 x, converted in-register)
  gemm_a32_kernel<<<dim3(32, 18), 256, 0, stream>>>(
      x, wqkvb, qkvb, 4096, 2304, 768);

  // 2) flash attention with elevation bias -> normalized bf16 aob
  attn_kernel<<<dim3(24, 8), 512, 0, stream>>>(qkvb, elev, alpha, aob);

  // 3) out = aob @ w_proj^T + b_proj
  gemm2_kernel<<<dim3(64, 6), 256, 0, stream>>>(
      aob, wprojb, b_proj, out, 4096, 768, 768);
}